// Round 1
// baseline (162.759 us; speedup 1.0000x reference)
//
#include <hip/hip_runtime.h>
#include <math.h>

#define DD 768            // hidden dim
#define S_LEN 512         // sequence length
#define NF4 3             // float4 chunks per lane: 768 / (64*4)
#define NACC (2 * DD + 1) // u[768], p[768], num_tok = 1537
#define PW 1544           // partial row stride (floats), 8-aligned
#define GMAIN 512         // main-pass grid (2 blocks/CU, 8 waves/CU)
#define NWAVES (GMAIN * 4)
#define NYB 16            // tail y-blocks
#define BCHUNK (GMAIN / NYB) // partial rows per tail block (32)
#define NXB 7             // tail x-blocks (7*256 >= NACC)
#define TAILBLOCKS (NXB * NYB)

// One wave per token-stream; lane l owns d-indices {k*256 + l*4 + j}.
// R4: the controllable slice (~19us of the 154us total; rest is harness
// d_ws re-poison at 402MB/59us + d_in restore) is main_pass at the HBM
// read floor (~14.3us for the ~90MB of label!=0 logits) plus the tail.
// This round: fuse reduce_partials+finalize into one kernel via an
// atomic-ticket last-block finalize -- removes one launch gap and one
// single-block kernel ramp. Arithmetic order is bit-identical.
__global__ __launch_bounds__(256) void main_pass(const float* __restrict__ logits,
                                                 const int* __restrict__ labels,
                                                 const int* __restrict__ eid_p,
                                                 int ntok,
                                                 float* __restrict__ partial,
                                                 unsigned int* __restrict__ done) {
    // zero the tail's ticket counter; visible to the tail kernel because
    // dispatch boundaries on a stream are coherence points.
    if (blockIdx.x == 0 && threadIdx.x == 0) *done = 0u;

    const int eid  = *eid_p;
    const int lane = threadIdx.x & 63;
    const int wid  = threadIdx.x >> 6;
    const int gw   = blockIdx.x * 4 + wid;   // global wave id

    // prefetch this wave's labels: lane j holds labels[gw + j*NWAVES], j<16
    int lblv = 0;
    if (lane < 16) {
        const int tj = gw + lane * NWAVES;
        if (tj < ntok) lblv = labels[tj];
    }

    float u_acc[12], p_acc[12];
#pragma unroll
    for (int j = 0; j < 12; ++j) { u_acc[j] = 0.f; p_acc[j] = 0.f; }
    float tokcnt = 0.f;

    for (int j = 0;; ++j) {
        const int t = gw + j * NWAVES;
        if (t >= ntok) break;
        const int lbl = (j < 16) ? __shfl(lblv, j, 64) : labels[t];

        // token contributes iff it has a nonzero label (cos-sim term) or is a
        // proto token (lbl==eid; only possible here with lbl==0 if eid==0)
        if (lbl == 0 && eid != 0) continue;   // wave-uniform skip, ~10% of tokens

        const float4* src = (const float4*)(logits + (size_t)t * DD);
        float4 f[NF4];
#pragma unroll
        for (int k = 0; k < NF4; ++k) f[k] = src[k * 64 + lane];

        float ss = 0.f;
#pragma unroll
        for (int k = 0; k < NF4; ++k)
            ss += f[k].x * f[k].x + f[k].y * f[k].y + f[k].z * f[k].z + f[k].w * f[k].w;
#pragma unroll
        for (int o = 32; o > 0; o >>= 1) ss += __shfl_xor(ss, o, 64);

        if (lbl != 0) {                        // wave-uniform
            const float inv = (ss > 0.f) ? rsqrtf(ss) : 0.f;
            tokcnt += 1.f;
#pragma unroll
            for (int k = 0; k < NF4; ++k) {
                u_acc[4 * k + 0] += f[k].x * inv;
                u_acc[4 * k + 1] += f[k].y * inv;
                u_acc[4 * k + 2] += f[k].z * inv;
                u_acc[4 * k + 3] += f[k].w * inv;
            }
        }
        if (lbl == eid && (t & (S_LEN - 1)) != 0) {  // wave-uniform, ~10%
#pragma unroll
            for (int k = 0; k < NF4; ++k) {
                p_acc[4 * k + 0] += f[k].x;
                p_acc[4 * k + 1] += f[k].y;
                p_acc[4 * k + 2] += f[k].z;
                p_acc[4 * k + 3] += f[k].w;
            }
        }
    }

    // ---- block combine in LDS (4 waves take turns; lanes write disjoint d) ----
    __shared__ float sh[NACC];
    for (int i = threadIdx.x; i < NACC; i += 256) sh[i] = 0.f;
    __syncthreads();
    for (int w = 0; w < 4; ++w) {
        if (wid == w) {
#pragma unroll
            for (int k = 0; k < NF4; ++k) {
                const int d = k * 256 + lane * 4;
                sh[d + 0]      += u_acc[4 * k + 0];
                sh[d + 1]      += u_acc[4 * k + 1];
                sh[d + 2]      += u_acc[4 * k + 2];
                sh[d + 3]      += u_acc[4 * k + 3];
                sh[DD + d + 0] += p_acc[4 * k + 0];
                sh[DD + d + 1] += p_acc[4 * k + 1];
                sh[DD + d + 2] += p_acc[4 * k + 2];
                sh[DD + d + 3] += p_acc[4 * k + 3];
            }
            if (lane == 0) sh[2 * DD] += tokcnt;
        }
        __syncthreads();
    }

    // ---- plain coalesced store of this block's partial row ----
    float* row = partial + (size_t)blockIdx.x * PW;
    for (int i = threadIdx.x; i < NACC; i += 256) row[i] = sh[i];
}

// Fused tail: grid (NXB, NYB). Each block sums BCHUNK partial rows for its
// 256-dim chunk into acc2[y] (disjoint outputs, no atomics on data), then
// the LAST block to finish (atomic ticket) folds the NYB acc2 rows and
// computes the final scalar -- identical arithmetic to the old
// reduce_partials + finalize pair, one launch instead of two.
__global__ __launch_bounds__(256) void tail(const float* __restrict__ partial,
                                            float* __restrict__ acc2,
                                            unsigned int* __restrict__ done,
                                            float* __restrict__ out) {
    const int i = blockIdx.x * 256 + threadIdx.x;
    if (i < NACC) {
        const int b0 = blockIdx.y * BCHUNK;
        float s0 = 0.f, s1 = 0.f, s2 = 0.f, s3 = 0.f;
#pragma unroll 4
        for (int j = 0; j < BCHUNK; j += 4) {
            s0 += partial[(size_t)(b0 + j + 0) * PW + i];
            s1 += partial[(size_t)(b0 + j + 1) * PW + i];
            s2 += partial[(size_t)(b0 + j + 2) * PW + i];
            s3 += partial[(size_t)(b0 + j + 3) * PW + i];
        }
        acc2[(size_t)blockIdx.y * PW + i] = (s0 + s1) + (s2 + s3);
    }

    // release: every thread fences its own acc2 store to device scope
    // (per-XCD L2s are not coherent without this), then thread 0 takes a
    // ticket. Last ticket-holder block does the finalize.
    __threadfence();
    __syncthreads();
    __shared__ int lastBlk;
    if (threadIdx.x == 0) {
        unsigned int old = atomicAdd(done, 1u);
        lastBlk = (old == TAILBLOCKS - 1) ? 1 : 0;
    }
    __syncthreads();
    if (!lastBlk) return;
    __threadfence();   // acquire: see all other blocks' acc2 stores

    const int tid = threadIdx.x;
    double dup = 0.0, dpp = 0.0;
    for (int d = tid; d < DD; d += 256) {
        float u = 0.f, p = 0.f;
#pragma unroll
        for (int y = 0; y < NYB; ++y) {
            u += acc2[(size_t)y * PW + d];
            p += acc2[(size_t)y * PW + DD + d];
        }
        dup += (double)u * (double)p;
        dpp += (double)p * (double)p;
    }
#pragma unroll
    for (int o = 32; o > 0; o >>= 1) {
        dup += __shfl_down(dup, o, 64);
        dpp += __shfl_down(dpp, o, 64);
    }
    __shared__ double s_up[4], s_pp[4];
    const int lane = tid & 63, wid = tid >> 6;
    if (lane == 0) { s_up[wid] = dup; s_pp[wid] = dpp; }
    __syncthreads();
    if (tid == 0) {
        double up = 0.0, pp = 0.0;
        for (int w = 0; w < 4; ++w) { up += s_up[w]; pp += s_pp[w]; }
        float cnt = 0.f;
#pragma unroll
        for (int y = 0; y < NYB; ++y) cnt += acc2[(size_t)y * PW + 2 * DD];
        float res = 0.f;
        if (pp > 0.0) res = (float)(up / (sqrt(pp) * (double)fmaxf(cnt, 1.f)));
        out[0] = res;
    }
}

extern "C" void kernel_launch(void* const* d_in, const int* in_sizes, int n_in,
                              void* d_out, int out_size, void* d_ws, size_t ws_size,
                              hipStream_t stream) {
    const float* logits = (const float*)d_in[0];
    const int*   labels = (const int*)d_in[1];
    const int*   eid    = (const int*)d_in[2];
    const int ntok = in_sizes[1];          // B*S = 32768

    float* partial = (float*)d_ws;                                   // GMAIN x PW (~3.2 MB)
    float* acc2    = (float*)d_ws + (size_t)GMAIN * PW;              // NYB x PW (~99 KB)
    unsigned int* done = (unsigned int*)((float*)d_ws + (size_t)(GMAIN + NYB) * PW);

    main_pass<<<GMAIN, 256, 0, stream>>>(logits, labels, eid, ntok, partial, done);
    tail<<<dim3(NXB, NYB), 256, 0, stream>>>(partial, acc2, done, (float*)d_out);
}